// Round 1
// baseline (267.139 us; speedup 1.0000x reference)
//
#include <hip/hip_runtime.h>
#include <math.h>

#define D 64
#define BD 12
#define NA 10000
#define NE 40000

__device__ __forceinline__ unsigned enc_ord(float f){
  unsigned u = __float_as_uint(f);
  return (u & 0x80000000u) ? ~u : (u | 0x80000000u);
}
__device__ __forceinline__ float dec_ord(unsigned u){
  unsigned v = (u & 0x80000000u) ? (u ^ 0x80000000u) : ~u;
  return __uint_as_float(v);
}

// ---------------- fold BN into weights, build transposed layouts ----------------
__global__ void k_fold(const float* __restrict__ encW, const float* __restrict__ encB,
                       const float* __restrict__ eg, const float* __restrict__ ebt,
                       const float* __restrict__ em, const float* __restrict__ ev,
                       const float* __restrict__ attW, const float* __restrict__ attB,
                       const float* __restrict__ agm, const float* __restrict__ abt,
                       const float* __restrict__ amn, const float* __restrict__ avr,
                       const float* __restrict__ wih, const float* __restrict__ whh,
                       float* __restrict__ encWf, float* __restrict__ encBf,
                       float* __restrict__ attWt, float* __restrict__ attBf,
                       float* __restrict__ gruWt)
{
  int i = blockIdx.x*blockDim.x + threadIdx.x;
  int stride = gridDim.x*blockDim.x;
  for (int idx=i; idx<4096*12; idx+=stride){
    int j = idx/12;
    float s = eg[j]*rsqrtf(ev[j]+1e-6f);
    encWf[idx] = encW[idx]*s;
  }
  for (int j=i; j<4096; j+=stride){
    float s = eg[j]*rsqrtf(ev[j]+1e-6f);
    encBf[j] = (encB[j]-em[j])*s + ebt[j];
  }
  for (int idx=i; idx<4096; idx+=stride){
    int k = idx>>6, f = idx&63;
    float s = agm[f]*rsqrtf(avr[f]+1e-6f);
    attWt[idx] = attW[f*64+k]*s;
  }
  for (int f=i; f<64; f+=stride){
    float s = agm[f]*rsqrtf(avr[f]+1e-6f);
    attBf[f] = (attB[f]-amn[f])*s + abt[f];
  }
  // gruWt[k*384 + g*64 + f]; g<3 -> W_ih row g*64+f, g>=3 -> W_hh row (g-3)*64+f
  for (int idx=i; idx<64*6*64; idx+=stride){
    int k = idx/384;
    int rem = idx - k*384;
    int g = rem>>6, f = rem&63;
    gruWt[idx] = (g<3) ? wih[(g*64+f)*64+k] : whh[((g-3)*64+f)*64+k];
  }
}

// ---------------- per-edge: fused enc GEMM + contraction + score + segmax ----------------
// block = 256 threads (4 waves), 32 edges/block, 8 edges/wave.
// W' staged in LDS in 4 passes of 16 d-rows (48KB each).
__global__ __launch_bounds__(256) void k_edge(
  const float* __restrict__ atom, const int* __restrict__ bidx, const float* __restrict__ bond,
  const float* __restrict__ encWf, const float* __restrict__ encBf,
  const float* __restrict__ alW, const float* __restrict__ alB,
  float* __restrict__ neighbor, float* __restrict__ scorev, unsigned* __restrict__ segmax)
{
  __shared__ float sW[12288];       // 16 d x 64 f x 12  (48KB)
  __shared__ float sB[1024];        // bias chunk
  __shared__ float sAtom[32][64];   // neighbor-atom features
  __shared__ float sBond[32][12];
  __shared__ int   sIdx[64];        // tgt,nbr interleaved

  int tid = threadIdx.x;
  int f = tid & 63;
  int wv = tid >> 6;
  int e0 = blockIdx.x * 32;

  if (tid < 64){
    int gi = e0*2 + tid;
    sIdx[tid] = (gi < NE*2) ? bidx[gi] : 0;
  }
  for (int idx=tid; idx<32*12; idx+=256){
    int e = idx/12, b = idx - e*12;
    int ge = e0+e;
    sBond[e][b] = (ge<NE) ? bond[ge*12+b] : 0.f;
  }
  __syncthreads();
  for (int idx=tid; idx<32*64; idx+=256){
    int e = idx>>6, ff = idx&63;
    int nb = sIdx[e*2+1];
    sAtom[e][ff] = atom[nb*64+ff];
  }

  int ew = wv*8;
  float bnd[8][12];
  #pragma unroll
  for (int i2=0;i2<8;i2++)
    #pragma unroll
    for (int j=0;j<12;j++)
      bnd[i2][j] = sBond[ew+i2][j];

  float acc[8] = {0,0,0,0,0,0,0,0};

  for (int pass=0; pass<4; pass++){
    __syncthreads();
    const float4* src = (const float4*)(encWf + pass*12288);
    float4* dst = (float4*)sW;
    for (int idx=tid; idx<3072; idx+=256) dst[idx] = src[idx];
    for (int idx=tid; idx<1024; idx+=256) sB[idx] = encBf[pass*1024+idx];
    __syncthreads();
    for (int dl=0; dl<16; dl++){
      const float* wr = &sW[(dl*64+f)*12];
      float4 w0 = *(const float4*)(wr);
      float4 w1 = *(const float4*)(wr+4);
      float4 w2 = *(const float4*)(wr+8);
      float w[12];
      w[0]=w0.x; w[1]=w0.y; w[2]=w0.z; w[3]=w0.w;
      w[4]=w1.x; w[5]=w1.y; w[6]=w1.z; w[7]=w1.w;
      w[8]=w2.x; w[9]=w2.y; w[10]=w2.z; w[11]=w2.w;
      float bb = sB[dl*64+f];
      #pragma unroll
      for (int i2=0;i2<8;i2++){
        float t = bb;
        #pragma unroll
        for (int j=0;j<12;j++) t = fmaf(bnd[i2][j], w[j], t);
        t = fmaxf(t, 0.f);
        acc[i2] = fmaf(sAtom[ew+i2][pass*16+dl], t, acc[i2]);
      }
    }
  }

  float wa = alW[f], wn = alW[64+f];
  float ab = alB[0];
  #pragma unroll
  for (int i2=0;i2<8;i2++){
    int e = e0+ew+i2;
    if (e<NE){
      neighbor[e*64+f] = acc[i2];
      int tg = sIdx[(ew+i2)*2];
      float p = wa*atom[tg*64+f] + wn*acc[i2];
      #pragma unroll
      for (int off=32; off>0; off>>=1) p += __shfl_down(p, off);
      if (f==0){
        float s = p + ab;
        s = (s>0.f) ? s : 0.01f*s;
        scorev[e] = s;
        atomicMax(&segmax[tg], enc_ord(s));
      }
    }
  }
}

// ---------------- per-edge: exp, attd matvec, atomic accumulate ----------------
__global__ __launch_bounds__(256) void k_attn(
  const float* __restrict__ neighbor, const float* __restrict__ scorev,
  const unsigned* __restrict__ segmax, const int* __restrict__ bidx,
  const float* __restrict__ attWt, const float* __restrict__ attBf,
  float* __restrict__ ctx, float* __restrict__ denom)
{
  int tid = threadIdx.x;
  int f = tid & 63;
  int wv = __builtin_amdgcn_readfirstlane(tid >> 6);
  float wcol[64];
  #pragma unroll
  for (int k=0;k<64;k++) wcol[k] = attWt[k*64+f];
  float bf = attBf[f];
  int stride = gridDim.x*4;
  for (int e = blockIdx.x*4 + wv; e < NE; e += stride){
    const float* nrow = neighbor + e*64;
    float attd = bf;
    #pragma unroll
    for (int k=0;k<64;k++) attd = fmaf(nrow[k], wcol[k], attd);
    int tg = bidx[e*2];
    float mx = dec_ord(segmax[tg]);
    float ex = expf(scorev[e] - mx);
    atomicAdd(&ctx[tg*64+f], ex*attd);
    if (f==0) atomicAdd(&denom[tg], ex);
  }
}

// ---------------- per-atom: elu(context) + GRU ----------------
__global__ __launch_bounds__(256) void k_gru(
  const float* __restrict__ atom, const float* __restrict__ ctxacc,
  const float* __restrict__ denom, const float* __restrict__ gruWt,
  const float* __restrict__ bih, const float* __restrict__ bhh,
  float* __restrict__ out)
{
  __shared__ float sh[4][2][64];
  int tid = threadIdx.x;
  int f = tid & 63;
  int wv = tid >> 6;
  int base = blockIdx.x*4;
  int stride = gridDim.x*4;
  int niter = (NA - base + stride - 1)/stride;
  if (base >= NA) niter = 0;
  for (int it=0; it<niter; it++){
    int a = base + wv + it*stride;
    float cf=0.f, hf=0.f;
    if (a<NA){
      float dn = denom[a] + 1e-8f;
      cf = ctxacc[a*64+f]/dn;
      cf = (cf>0.f) ? cf : expm1f(cf);
      hf = atom[a*64+f];
    }
    sh[wv][0][f]=cf; sh[wv][1][f]=hf;
    __syncthreads();
    float g0=0,g1=0,g2=0,g3=0,g4=0,g5=0;
    for (int k=0;k<64;k++){
      float ck = sh[wv][0][k], hk = sh[wv][1][k];
      const float* wr = gruWt + k*384 + f;
      g0 = fmaf(ck, wr[0],   g0);
      g1 = fmaf(ck, wr[64],  g1);
      g2 = fmaf(ck, wr[128], g2);
      g3 = fmaf(hk, wr[192], g3);
      g4 = fmaf(hk, wr[256], g4);
      g5 = fmaf(hk, wr[320], g5);
    }
    __syncthreads();
    if (a<NA){
      float r = 1.f/(1.f+expf(-(g0+bih[f]    +g3+bhh[f])));
      float z = 1.f/(1.f+expf(-(g1+bih[64+f] +g4+bhh[64+f])));
      float n = tanhf(g2+bih[128+f] + r*(g5+bhh[128+f]));
      out[a*64+f] = (1.f-z)*n + z*hf;
    }
  }
}

extern "C" void kernel_launch(void* const* d_in, const int* in_sizes, int n_in,
                              void* d_out, int out_size, void* d_ws, size_t ws_size,
                              hipStream_t stream) {
  const float*    atom = (const float*)d_in[0];
  const int*      bidx = (const int*)  d_in[1];
  const float*    bond = (const float*)d_in[2];
  const float*    encW = (const float*)d_in[3];
  const float*    encB = (const float*)d_in[4];
  const float*    eg   = (const float*)d_in[5];
  const float*    ebt  = (const float*)d_in[6];
  const float*    em   = (const float*)d_in[7];
  const float*    ev   = (const float*)d_in[8];
  const float*    alW  = (const float*)d_in[9];
  const float*    alB  = (const float*)d_in[10];
  const float*    atW  = (const float*)d_in[11];
  const float*    atB  = (const float*)d_in[12];
  const float*    agm  = (const float*)d_in[13];
  const float*    abt  = (const float*)d_in[14];
  const float*    amn  = (const float*)d_in[15];
  const float*    avr  = (const float*)d_in[16];
  const float*    wih  = (const float*)d_in[17];
  const float*    whh  = (const float*)d_in[18];
  const float*    bih  = (const float*)d_in[19];
  const float*    bhh  = (const float*)d_in[20];

  float* ws = (float*)d_ws;
  float* encWf    = ws;                  // 49152
  float* encBf    = encWf + 49152;       // 4096
  float* attWt    = encBf + 4096;        // 4096
  float* attBf    = attWt + 4096;        // 64
  float* gruWt    = attBf + 64;          // 24576
  float* neighbor = gruWt + 24576;       // 2,560,000
  float* scorev   = neighbor + 2560000;  // 40,000
  unsigned* segmax= (unsigned*)(scorev + 40000); // 10,000
  float* denom    = (float*)(segmax + 10000);    // 10,000
  float* ctx      = denom + 10000;       // 640,000

  hipMemsetAsync(segmax, 0, 10000*sizeof(unsigned), stream);
  hipMemsetAsync(denom,  0, 10000*sizeof(float), stream);
  hipMemsetAsync(ctx,    0, 640000*sizeof(float), stream);

  k_fold<<<128, 256, 0, stream>>>(encW,encB,eg,ebt,em,ev,
                                  atW,atB,agm,abt,amn,avr,
                                  wih,whh,
                                  encWf,encBf,attWt,attBf,gruWt);
  k_edge<<<1250, 256, 0, stream>>>(atom,bidx,bond,encWf,encBf,alW,alB,
                                   neighbor,scorev,segmax);
  k_attn<<<1024, 256, 0, stream>>>(neighbor,scorev,segmax,bidx,attWt,attBf,ctx,denom);
  k_gru<<<512, 256, 0, stream>>>(atom,ctx,denom,gruWt,bih,bhh,(float*)d_out);
}

// Round 2
// 245.857 us; speedup vs baseline: 1.0866x; 1.0866x over previous
//
#include <hip/hip_runtime.h>
#include <math.h>

#define NA 10000
#define NE 40000

typedef float f4 __attribute__((ext_vector_type(4)));
typedef __bf16 bf16x8 __attribute__((ext_vector_type(8)));

union U8 { unsigned short us[8]; bf16x8 v; };

__device__ __forceinline__ unsigned short bf_rne(float x){
  unsigned u = __float_as_uint(x);
  unsigned r = (u + 0x7fffu + ((u>>16)&1u)) >> 16;
  return (unsigned short)r;
}
__device__ __forceinline__ float bf_to_f(unsigned short h){
  return __uint_as_float(((unsigned)h)<<16);
}
__device__ __forceinline__ unsigned enc_ord(float f){
  unsigned u = __float_as_uint(f);
  return (u & 0x80000000u) ? ~u : (u | 0x80000000u);
}
__device__ __forceinline__ float dec_ord(unsigned u){
  unsigned v = (u & 0x80000000u) ? (u ^ 0x80000000u) : ~u;
  return __uint_as_float(v);
}

// ---------------- fold BN into weights; build MFMA fragment tables ----------------
// B1frag/B2frag: enc GEMM B-operands, frag layout [tile t(256)][lane(64)][j(8)] bf16.
//   B row k (k=(lane>>4)*8+j, n=t*16+(lane&15)):
//   B1: k<12 -> w_hi[k][n]; 12<=k<24 -> w_hi[k-12][n]; k==24 -> bias_hi; k==25 -> bias_lo; else 0
//   B2: k<12 -> w_lo[k][n]; else 0
// attB1/attB2: attd GEMM B-operands [nt(4)][kf(2)][lane][j] bf16 (hi/lo of folded att_W^T)
// wq: GRU weights [g(6)][kg(16)][f(64)][j(4)] fp32 for b128 LDS reads
__global__ void k_fold(const float* __restrict__ encW, const float* __restrict__ encB,
                       const float* __restrict__ eg, const float* __restrict__ ebt,
                       const float* __restrict__ em, const float* __restrict__ ev,
                       const float* __restrict__ attW, const float* __restrict__ attB,
                       const float* __restrict__ agm, const float* __restrict__ abt,
                       const float* __restrict__ amn, const float* __restrict__ avr,
                       const float* __restrict__ wih, const float* __restrict__ whh,
                       unsigned short* __restrict__ B1, unsigned short* __restrict__ B2,
                       unsigned short* __restrict__ aB1, unsigned short* __restrict__ aB2,
                       float* __restrict__ attBf, float* __restrict__ wq)
{
  int i0 = blockIdx.x*blockDim.x + threadIdx.x;
  int stride = gridDim.x*blockDim.x;
  for (int i=i0; i<131072; i+=stride){
    int t = i>>9, r = i&511, l = r>>3, j = r&7;
    int k = ((l>>4)<<3)+j, n = (t<<4)+(l&15);
    float s = eg[n]*rsqrtf(ev[n]+1e-6f);
    unsigned short v1=0, v2=0;
    if (k<12){
      float w = encW[n*12+k]*s;
      unsigned short hi = bf_rne(w);
      v1 = hi;
      v2 = bf_rne(w - bf_to_f(hi));
    } else if (k<24){
      float w = encW[n*12+(k-12)]*s;
      v1 = bf_rne(w);
    } else if (k==24){
      float b = (encB[n]-em[n])*s + ebt[n];
      v1 = bf_rne(b);
    } else if (k==25){
      float b = (encB[n]-em[n])*s + ebt[n];
      unsigned short hi = bf_rne(b);
      v1 = bf_rne(b - bf_to_f(hi));
    }
    B1[i] = v1; B2[i] = v2;
  }
  for (int i=i0; i<4096; i+=stride){
    int j = i&7, l = (i>>3)&63, kfnt = i>>9;
    int kf = kfnt&1, nt = kfnt>>1;
    int k = kf*32 + ((l>>4)<<3) + j;
    int n = (nt<<4) + (l&15);
    float s = agm[n]*rsqrtf(avr[n]+1e-6f);
    float w = attW[n*64+k]*s;
    unsigned short hi = bf_rne(w);
    aB1[i] = hi;
    aB2[i] = bf_rne(w - bf_to_f(hi));
  }
  for (int n=i0; n<64; n+=stride){
    float s = agm[n]*rsqrtf(avr[n]+1e-6f);
    attBf[n] = (attB[n]-amn[n])*s + abt[n];
  }
  for (int i=i0; i<24576; i+=stride){
    int j=i&3, f=(i>>2)&63, idx2=i>>8;
    int g=idx2>>4, kg=idx2&15, k=kg*4+j;
    wq[i] = (g<3)? wih[(g*64+f)*64+k] : whh[((g-3)*64+f)*64+k];
  }
}

// ---------------- per-edge: MFMA enc GEMM + contraction + score + attd ----------------
// 64 edges/block (4 waves x 16-edge M-tile), full N=4096 sweep per wave.
__global__ __launch_bounds__(256) void k_edge(
  const float* __restrict__ atom, const int* __restrict__ bidx, const float* __restrict__ bond,
  const unsigned short* __restrict__ B1g, const unsigned short* __restrict__ B2g,
  const unsigned short* __restrict__ aB1g, const unsigned short* __restrict__ aB2g,
  const float* __restrict__ attBf,
  const float* __restrict__ alW, const float* __restrict__ alB,
  float* __restrict__ attd, float* __restrict__ scorev, unsigned* __restrict__ segmax)
{
  // union region: atomT [d(64)][stride 68] then neighbor [e(64)][stride 68]
  __shared__ float sU[64*68];
  __shared__ int   sIdx[128];
  __shared__ float sPn[64];

  int tid = threadIdx.x;
  int l = tid & 63;
  int w = tid >> 6;
  int lm = l & 15;
  int g  = l >> 4;
  int E0 = blockIdx.x * 64;   // 625 blocks * 64 = 40000 exactly

  if (tid < 128) sIdx[tid] = bidx[E0*2 + tid];
  __syncthreads();
  // stage atom[nbr[e]] transposed: sU[d*68 + e]
  for (int i=tid; i<4096; i+=256){
    int d = i&63, e = i>>6;   // e 0..15 per pass? no: i>>6 covers 0..63 over 16 iters
    int nb = sIdx[e*2+1];
    sU[d*68 + e] = atom[(size_t)nb*64 + d];
  }

  // build A fragments for this wave's 16-edge M-tile (edge = E0 + w*16 + lm)
  U8 A1, A2;
  {
    int er = E0 + w*16 + lm;
    const f4* bp = (const f4*)(bond + (size_t)er*12);
    f4 b0=bp[0], b1v=bp[1], b2v=bp[2];
    float bv[12] = {b0.x,b0.y,b0.z,b0.w,b1v.x,b1v.y,b1v.z,b1v.w,b2v.x,b2v.y,b2v.z,b2v.w};
    unsigned short hi[12], lo[12];
    #pragma unroll
    for (int j=0;j<12;j++){ hi[j]=bf_rne(bv[j]); lo[j]=bf_rne(bv[j]-bf_to_f(hi[j])); }
    #pragma unroll
    for (int j=0;j<8;j++){
      unsigned short c0 = hi[j];
      unsigned short c1 = (j<4)? hi[8+j] : lo[(j-4)&7];
      unsigned short c2 = lo[4+j];
      unsigned short c3 = (j<2)? (unsigned short)0x3F80 : (unsigned short)0;
      A1.us[j] = (g==0)?c0:(g==1)?c1:(g==2)?c2:c3;
      unsigned short d1 = (j<4)? hi[8+j] : (unsigned short)0;
      A2.us[j] = (g==0)?c0:(g==1)?d1:(unsigned short)0;
    }
  }
  __syncthreads();

  // N sweep: d outer (atomn reuse), 4 f-groups inner
  f4 nacc[4];
  #pragma unroll
  for (int fg=0; fg<4; fg++) nacc[fg] = (f4){0.f,0.f,0.f,0.f};

  for (int d=0; d<64; d++){
    f4 an = *(const f4*)&sU[d*68 + w*16 + g*4];
    #pragma unroll
    for (int fg=0; fg<4; fg++){
      int t = d*4 + fg;
      U8 bb1, bb2;
      bb1.v = *(const bf16x8*)(B1g + ((size_t)(t*64+l))*8);
      bb2.v = *(const bf16x8*)(B2g + ((size_t)(t*64+l))*8);
      f4 c = (f4){0.f,0.f,0.f,0.f};
      c = __builtin_amdgcn_mfma_f32_16x16x32_bf16(A1.v, bb1.v, c, 0,0,0);
      c = __builtin_amdgcn_mfma_f32_16x16x32_bf16(A2.v, bb2.v, c, 0,0,0);
      #pragma unroll
      for (int r=0;r<4;r++){
        float evv = fmaxf(c[r], 0.f);
        nacc[fg][r] = fmaf(an[r], evv, nacc[fg][r]);
      }
    }
  }

  __syncthreads();   // all waves done reading atomT region

  // write neighbor tile: sU[e_loc*68 + f]
  #pragma unroll
  for (int fg=0; fg<4; fg++)
    #pragma unroll
    for (int r=0;r<4;r++)
      sU[(w*16 + g*4 + r)*68 + fg*16 + lm] = nacc[fg][r];

  // neighbor part of score: p_n[e] = sum_f alW[64+f]*nb[e][f]
  {
    float alwn[4];
    #pragma unroll
    for (int fg=0; fg<4; fg++) alwn[fg] = alW[64 + fg*16 + lm];
    #pragma unroll
    for (int r=0;r<4;r++){
      float p = nacc[0][r]*alwn[0] + nacc[1][r]*alwn[1] + nacc[2][r]*alwn[2] + nacc[3][r]*alwn[3];
      p += __shfl_xor(p, 1); p += __shfl_xor(p, 2);
      p += __shfl_xor(p, 4); p += __shfl_xor(p, 8);
      if (lm == 0) sPn[w*16 + g*4 + r] = p;
    }
  }
  __syncthreads();

  // score: lane (m=lm, q=g): partial over f = q*16..+15 of atom[tgt]·alW
  {
    int m = lm, q = g;
    int tg = sIdx[(w*16 + m)*2];
    const f4* ap = (const f4*)(atom + (size_t)tg*64 + q*16);
    const f4* wp = (const f4*)(alW + q*16);
    float pt = 0.f;
    #pragma unroll
    for (int qq=0; qq<4; qq++){
      f4 a4 = ap[qq], w4 = wp[qq];
      pt += a4.x*w4.x + a4.y*w4.y + a4.z*w4.z + a4.w*w4.w;
    }
    pt += __shfl_xor(pt, 16); pt += __shfl_xor(pt, 32);
    float s = pt + sPn[w*16 + m] + alB[0];
    s = (s > 0.f) ? s : 0.01f*s;
    if (q == 0){
      scorev[E0 + w*16 + m] = s;
      atomicMax(&segmax[tg], enc_ord(s));
    }
  }

  // attd = bn(neighbor @ attW^T) via MFMA (hi/lo), from LDS neighbor tile
  {
    U8 Ah[2], Al[2];
    const float* nr = &sU[(w*16 + lm)*68];
    #pragma unroll
    for (int kf=0; kf<2; kf++){
      f4 x0 = *(const f4*)&nr[kf*32 + g*8];
      f4 x1 = *(const f4*)&nr[kf*32 + g*8 + 4];
      float xv[8] = {x0.x,x0.y,x0.z,x0.w,x1.x,x1.y,x1.z,x1.w};
      #pragma unroll
      for (int j=0;j<8;j++){
        unsigned short hh = bf_rne(xv[j]);
        Ah[kf].us[j] = hh;
        Al[kf].us[j] = bf_rne(xv[j] - bf_to_f(hh));
      }
    }
    #pragma unroll
    for (int nt=0; nt<4; nt++){
      U8 b1k0,b1k1,b2k0,b2k1;
      b1k0.v = *(const bf16x8*)(aB1g + ((size_t)((nt*2+0)*64+l))*8);
      b1k1.v = *(const bf16x8*)(aB1g + ((size_t)((nt*2+1)*64+l))*8);
      b2k0.v = *(const bf16x8*)(aB2g + ((size_t)((nt*2+0)*64+l))*8);
      b2k1.v = *(const bf16x8*)(aB2g + ((size_t)((nt*2+1)*64+l))*8);
      f4 c = (f4){0.f,0.f,0.f,0.f};
      c = __builtin_amdgcn_mfma_f32_16x16x32_bf16(Ah[0].v, b1k0.v, c, 0,0,0);
      c = __builtin_amdgcn_mfma_f32_16x16x32_bf16(Ah[1].v, b1k1.v, c, 0,0,0);
      c = __builtin_amdgcn_mfma_f32_16x16x32_bf16(Al[0].v, b1k0.v, c, 0,0,0);
      c = __builtin_amdgcn_mfma_f32_16x16x32_bf16(Al[1].v, b1k1.v, c, 0,0,0);
      c = __builtin_amdgcn_mfma_f32_16x16x32_bf16(Ah[0].v, b2k0.v, c, 0,0,0);
      c = __builtin_amdgcn_mfma_f32_16x16x32_bf16(Ah[1].v, b2k1.v, c, 0,0,0);
      float bias = attBf[nt*16 + lm];
      #pragma unroll
      for (int r=0;r<4;r++){
        int eg2 = E0 + w*16 + g*4 + r;
        attd[(size_t)eg2*64 + nt*16 + lm] = c[r] + bias;
      }
    }
  }
}

// ---------------- per-edge: exp + atomic accumulate ----------------
__global__ __launch_bounds__(256) void k_attn(
  const float* __restrict__ attd, const float* __restrict__ scorev,
  const unsigned* __restrict__ segmax, const int* __restrict__ bidx,
  float* __restrict__ ctx, float* __restrict__ denom)
{
  int tid = threadIdx.x;
  int f = tid & 63;
  int w = tid >> 6;
  int stride = gridDim.x*4;
  for (int e = blockIdx.x*4 + w; e < NE; e += stride){
    int tg = bidx[e*2];
    float mx = dec_ord(segmax[tg]);
    float ex = expf(scorev[e] - mx);
    float ad = attd[(size_t)e*64 + f];
    atomicAdd(&ctx[(size_t)tg*64 + f], ex*ad);
    if (f == 0) atomicAdd(&denom[tg], ex);
  }
}

// ---------------- per-atom: elu(context) + GRU ----------------
// 32 atoms/block (4 waves x 8 atoms), weights staged in LDS, b128 reads.
__global__ __launch_bounds__(256) void k_gru(
  const float* __restrict__ atom, const float* __restrict__ ctxacc,
  const float* __restrict__ denom, const float* __restrict__ wqG,
  const float* __restrict__ bih, const float* __restrict__ bhh,
  float* __restrict__ out)
{
  __shared__ float swq[24576];
  __shared__ float sc[4][8][64];
  __shared__ float shh[4][8][64];
  int tid = threadIdx.x;
  int f = tid & 63;
  int w = tid >> 6;
  for (int i=tid; i<6144; i+=256) ((f4*)swq)[i] = ((const f4*)wqG)[i];
  int base = blockIdx.x*32 + w*8;
  #pragma unroll
  for (int a=0; a<8; a++){
    int ga = base + a;
    float cf=0.f, hf=0.f;
    if (ga < NA){
      float dn = denom[ga] + 1e-8f;
      cf = ctxacc[(size_t)ga*64 + f] / dn;
      cf = (cf > 0.f) ? cf : expm1f(cf);
      hf = atom[(size_t)ga*64 + f];
    }
    sc[w][a][f] = cf; shh[w][a][f] = hf;
  }
  __syncthreads();

  float acc[6][8];
  #pragma unroll
  for (int gg=0;gg<6;gg++)
    #pragma unroll
    for (int a=0;a<8;a++) acc[gg][a] = 0.f;

  for (int kg=0; kg<16; kg++){
    f4 wv[6];
    #pragma unroll
    for (int gg=0;gg<6;gg++) wv[gg] = *(const f4*)&swq[((gg*16+kg)*64 + f)*4];
    #pragma unroll
    for (int a=0;a<8;a++){
      f4 cv = *(const f4*)&sc[w][a][kg*4];
      f4 hv = *(const f4*)&shh[w][a][kg*4];
      #pragma unroll
      for (int j=0;j<4;j++){
        acc[0][a] = fmaf(cv[j], wv[0][j], acc[0][a]);
        acc[1][a] = fmaf(cv[j], wv[1][j], acc[1][a]);
        acc[2][a] = fmaf(cv[j], wv[2][j], acc[2][a]);
        acc[3][a] = fmaf(hv[j], wv[3][j], acc[3][a]);
        acc[4][a] = fmaf(hv[j], wv[4][j], acc[4][a]);
        acc[5][a] = fmaf(hv[j], wv[5][j], acc[5][a]);
      }
    }
  }

  float b0 = bih[f], b1 = bih[64+f], b2 = bih[128+f];
  float h0 = bhh[f], h1 = bhh[64+f], h2 = bhh[128+f];
  #pragma unroll
  for (int a=0;a<8;a++){
    int ga = base + a;
    if (ga < NA){
      float r = 1.f/(1.f + expf(-(acc[0][a] + b0 + acc[3][a] + h0)));
      float z = 1.f/(1.f + expf(-(acc[1][a] + b1 + acc[4][a] + h1)));
      float n = tanhf(acc[2][a] + b2 + r*(acc[5][a] + h2));
      out[(size_t)ga*64 + f] = (1.f - z)*n + z*shh[w][a][f];
    }
  }
}

extern "C" void kernel_launch(void* const* d_in, const int* in_sizes, int n_in,
                              void* d_out, int out_size, void* d_ws, size_t ws_size,
                              hipStream_t stream) {
  const float* atom = (const float*)d_in[0];
  const int*   bidx = (const int*)  d_in[1];
  const float* bond = (const float*)d_in[2];
  const float* encW = (const float*)d_in[3];
  const float* encB = (const float*)d_in[4];
  const float* eg   = (const float*)d_in[5];
  const float* ebt  = (const float*)d_in[6];
  const float* em   = (const float*)d_in[7];
  const float* ev   = (const float*)d_in[8];
  const float* alW  = (const float*)d_in[9];
  const float* alB  = (const float*)d_in[10];
  const float* atW  = (const float*)d_in[11];
  const float* atB  = (const float*)d_in[12];
  const float* agm  = (const float*)d_in[13];
  const float* abt  = (const float*)d_in[14];
  const float* amn  = (const float*)d_in[15];
  const float* avr  = (const float*)d_in[16];
  const float* wih  = (const float*)d_in[17];
  const float* whh  = (const float*)d_in[18];
  const float* bih  = (const float*)d_in[19];
  const float* bhh  = (const float*)d_in[20];

  float* ws = (float*)d_ws;
  unsigned short* B1f   = (unsigned short*)(ws + 0);        // 131072 ush (65536 f)
  unsigned short* B2f   = (unsigned short*)(ws + 65536);    // 131072 ush
  unsigned short* aB1   = (unsigned short*)(ws + 131072);   // 4096 ush (2048 f)
  unsigned short* aB2   = (unsigned short*)(ws + 133120);   // 4096 ush
  float* attBf    = ws + 135168;   // 64
  float* wq       = ws + 135232;   // 24576
  float* scorev   = ws + 159808;   // 40000
  unsigned* segmax= (unsigned*)(ws + 199808); // 10000
  float* denom    = ws + 209808;   // 10000
  float* ctx      = ws + 219808;   // 640000
  float* attd     = ws + 859808;   // 2560000

  hipMemsetAsync(segmax, 0, 10000*sizeof(unsigned), stream);
  hipMemsetAsync(denom,  0, 10000*sizeof(float), stream);
  hipMemsetAsync(ctx,    0, 640000*sizeof(float), stream);

  k_fold<<<512, 256, 0, stream>>>(encW,encB,eg,ebt,em,ev,
                                  atW,atB,agm,abt,amn,avr,
                                  wih,whh,
                                  B1f,B2f,aB1,aB2,attBf,wq);
  k_edge<<<625, 256, 0, stream>>>(atom,bidx,bond,B1f,B2f,aB1,aB2,attBf,
                                  alW,alB,attd,scorev,segmax);
  k_attn<<<2048, 256, 0, stream>>>(attd,scorev,segmax,bidx,ctx,denom);
  k_gru<<<313, 256, 0, stream>>>(atom,ctx,denom,wq,bih,bhh,(float*)d_out);
}

// Round 3
// 239.986 us; speedup vs baseline: 1.1131x; 1.0245x over previous
//
#include <hip/hip_runtime.h>
#include <math.h>

#define NA 10000
#define NE 40000

typedef float f4 __attribute__((ext_vector_type(4)));
typedef float f16v __attribute__((ext_vector_type(16)));
typedef __bf16 bf16x8 __attribute__((ext_vector_type(8)));

union U8 { unsigned short us[8]; bf16x8 v; };

__device__ __forceinline__ unsigned short bf_rne(float x){
  unsigned u = __float_as_uint(x);
  unsigned r = (u + 0x7fffu + ((u>>16)&1u)) >> 16;
  return (unsigned short)r;
}
__device__ __forceinline__ float bf_to_f(unsigned short h){
  return __uint_as_float(((unsigned)h)<<16);
}

// ---------------- fold BN into weights; build MFMA fragment tables ----------------
// Bh/Bl: enc GEMM B-operands for 32x32x16: [d(64)][ft(2)][lane(64)][j(8)] bf16.
//   B[k][n]: k=(lane>>5)*8+j, n_local=lane&31, f=ft*32+n_local, col n=d*64+f
//   k<12 -> Wfold[n][k] hi/lo; k==12 -> bias_fold[n] hi/lo; k>12 -> 0
// attWt: fp32 [k(64)][f(64)] folded att weights; attBf: folded bias
// wq: GRU weights [g(6)][kg(16)][f(64)][j(4)] fp32
__global__ void k_fold(const float* __restrict__ encW, const float* __restrict__ encB,
                       const float* __restrict__ eg, const float* __restrict__ ebt,
                       const float* __restrict__ em, const float* __restrict__ ev,
                       const float* __restrict__ attW, const float* __restrict__ attB,
                       const float* __restrict__ agm, const float* __restrict__ abt,
                       const float* __restrict__ amn, const float* __restrict__ avr,
                       const float* __restrict__ wih, const float* __restrict__ whh,
                       unsigned short* __restrict__ Bh, unsigned short* __restrict__ Bl,
                       float* __restrict__ attWt, float* __restrict__ attBf,
                       float* __restrict__ wq)
{
  int i0 = blockIdx.x*blockDim.x + threadIdx.x;
  int stride = gridDim.x*blockDim.x;
  for (int i=i0; i<65536; i+=stride){
    int j = i&7, l = (i>>3)&63, t = i>>9;
    int d = t>>1, ft = t&1;
    int k = ((l>>5)<<3)+j;
    int n = d*64 + ft*32 + (l&31);
    float s = eg[n]*rsqrtf(ev[n]+1e-6f);
    unsigned short vh=0, vl=0;
    if (k<12){
      float w = encW[n*12+k]*s;
      unsigned short hi = bf_rne(w);
      vh = hi; vl = bf_rne(w - bf_to_f(hi));
    } else if (k==12){
      float b = (encB[n]-em[n])*s + ebt[n];
      unsigned short hi = bf_rne(b);
      vh = hi; vl = bf_rne(b - bf_to_f(hi));
    }
    Bh[i] = vh; Bl[i] = vl;
  }
  for (int i=i0; i<4096; i+=stride){
    int k = i>>6, f = i&63;
    float s = agm[f]*rsqrtf(avr[f]+1e-6f);
    attWt[i] = attW[f*64+k]*s;
  }
  for (int f=i0; f<64; f+=stride){
    float s = agm[f]*rsqrtf(avr[f]+1e-6f);
    attBf[f] = (attB[f]-amn[f])*s + abt[f];
  }
  for (int i=i0; i<24576; i+=stride){
    int j=i&3, f=(i>>2)&63, idx2=i>>8;
    int g=idx2>>4, kg=idx2&15, k=kg*4+j;
    wq[i] = (g<3)? wih[(g*64+f)*64+k] : whh[((g-3)*64+f)*64+k];
  }
}

// ---------------- CSR build ----------------
__global__ void k_hist(const int* __restrict__ bidx, int* __restrict__ cnt){
  int e = blockIdx.x*blockDim.x + threadIdx.x;
  if (e < NE) atomicAdd(&cnt[bidx[e*2]], 1);
}

__global__ __launch_bounds__(256) void k_scan(const int* __restrict__ cnt,
                                              int* __restrict__ rowstart,
                                              int* __restrict__ wofs){
  __shared__ int sPart[256];
  int t = threadIdx.x;
  int lo = t*40;
  int hi = lo+40; if (hi > NA) hi = NA; if (lo > NA) lo = NA;
  int sum = 0;
  for (int i=lo;i<hi;i++) sum += cnt[i];
  sPart[t] = sum;
  __syncthreads();
  for (int off=1; off<256; off<<=1){
    int v = 0;
    if (t >= off) v = sPart[t-off];
    __syncthreads();
    if (t >= off) sPart[t] += v;
    __syncthreads();
  }
  int run = sPart[t] - sum;   // exclusive base
  for (int i=lo;i<hi;i++){
    rowstart[i] = run; wofs[i] = run;
    run += cnt[i];
  }
  if (t==255) rowstart[NA] = run;
}

__global__ void k_scatter(const int* __restrict__ bidx, int* __restrict__ wofs,
                          int* __restrict__ elist){
  int e = blockIdx.x*blockDim.x + threadIdx.x;
  if (e < NE){
    int tg = bidx[e*2];
    int pos = atomicAdd(&wofs[tg], 1);
    elist[pos] = e;
  }
}

// ---------------- per-edge: MFMA enc GEMM + contraction + score ----------------
// 32 edges/block, 4 waves each covering 16 d-values; 32x32x16 bf16 MFMA.
__global__ __launch_bounds__(256) void k_edge(
  const float* __restrict__ atom, const int* __restrict__ bidx, const float* __restrict__ bond,
  const unsigned short* __restrict__ Bhg, const unsigned short* __restrict__ Blg,
  const float* __restrict__ alW, const float* __restrict__ alB,
  float* __restrict__ neighbor, float* __restrict__ scorev)
{
  __shared__ float sA[64*33];     // atomT [d][e], stride 33
  __shared__ float sP[4*2048];    // per-wave partials, C layout
  __shared__ float sNb[32*65];    // neighbor tile [e][f], stride 65
  __shared__ int   sIdx[64];

  int tid = threadIdx.x;
  int l = tid & 63;
  int w = tid >> 6;
  int g = l >> 5;          // K-group (and m-half selector)
  int em = l & 31;         // A-fragment edge row
  int E0 = blockIdx.x * 32;   // 1250 blocks * 32 = 40000

  if (tid < 64) sIdx[tid] = bidx[E0*2 + tid];
  __syncthreads();
  for (int i=tid; i<2048; i+=256){
    int e = i>>6, d = i&63;
    int nb = sIdx[e*2+1];
    sA[d*33+e] = atom[(size_t)nb*64 + d];
  }

  // A fragments: edge = E0+em, k = g*8+j
  U8 A1, A2;
  {
    const f4* bp = (const f4*)(bond + (size_t)(E0+em)*12);
    f4 b0=bp[0], b1v=bp[1], b2v=bp[2];
    float bv[12] = {b0.x,b0.y,b0.z,b0.w,b1v.x,b1v.y,b1v.z,b1v.w,b2v.x,b2v.y,b2v.z,b2v.w};
    unsigned short hi[12], lo[12];
    #pragma unroll
    for (int j=0;j<12;j++){ hi[j]=bf_rne(bv[j]); lo[j]=bf_rne(bv[j]-bf_to_f(hi[j])); }
    #pragma unroll
    for (int j=0;j<8;j++){
      int k = g*8+j;
      A1.us[j] = (k<12)? hi[k] : (k==12? (unsigned short)0x3F80 : (unsigned short)0);
      A2.us[j] = (k<12)? lo[k] : (unsigned short)0;
    }
  }
  __syncthreads();

  f4 nacc[2][4];
  #pragma unroll
  for (int ft=0; ft<2; ft++)
    #pragma unroll
    for (int q=0;q<4;q++) nacc[ft][q] = (f4){0.f,0.f,0.f,0.f};

  int dbase = w*16;
  for (int dd=0; dd<16; dd++){
    int d = dbase + dd;
    f4 ldA[4];
    #pragma unroll
    for (int q=0;q<4;q++) ldA[q] = *(const f4*)&sA[d*33 + 8*q + 4*g];
    #pragma unroll
    for (int ft=0; ft<2; ft++){
      U8 bbh, bbl;
      bbh.v = *(const bf16x8*)(Bhg + ((size_t)((d*2+ft)*64 + l))*8);
      bbl.v = *(const bf16x8*)(Blg + ((size_t)((d*2+ft)*64 + l))*8);
      f16v c;
      #pragma unroll
      for (int r=0;r<16;r++) c[r] = 0.f;
      c = __builtin_amdgcn_mfma_f32_32x32x16_bf16(A1.v, bbh.v, c, 0,0,0);
      c = __builtin_amdgcn_mfma_f32_32x32x16_bf16(A2.v, bbh.v, c, 0,0,0);
      c = __builtin_amdgcn_mfma_f32_32x32x16_bf16(A1.v, bbl.v, c, 0,0,0);
      #pragma unroll
      for (int r=0;r<16;r++){
        float ev = fmaxf(c[r], 0.f);
        nacc[ft][r>>2][r&3] = fmaf(ldA[r>>2][r&3], ev, nacc[ft][r>>2][r&3]);
      }
    }
  }

  // dump partials
  #pragma unroll
  for (int ft=0; ft<2; ft++)
    #pragma unroll
    for (int r=0;r<16;r++)
      sP[w*2048 + ft*1024 + r*64 + l] = nacc[ft][r>>2][r&3];
  __syncthreads();

  // reduce 4 wave-partials, write neighbor tile [e][f]
  for (int idx=tid; idx<2048; idx+=256){
    float v = sP[idx] + sP[2048+idx] + sP[4096+idx] + sP[6144+idx];
    int ft = idx>>10, rl = idx&1023;
    int r = rl>>6, ll = rl&63;
    int m = (r&3) + 8*(r>>2) + 4*(ll>>5);
    int f = ft*32 + (ll&31);
    sNb[m*65 + f] = v;
  }
  __syncthreads();

  // write neighbor to global (coalesced)
  for (int i=tid; i<2048; i+=256){
    int e = i>>6, f = i&63;
    neighbor[(size_t)(E0+e)*64 + f] = sNb[e*65 + f];
  }

  // score: each wave handles 8 edges
  {
    float wa = alW[l], wn = alW[64+l];
    #pragma unroll
    for (int i=0;i<8;i++){
      int e = w*8 + i;
      int tg = sIdx[e*2];
      float p = wa*atom[(size_t)tg*64 + l] + wn*sNb[e*65 + l];
      p += __shfl_xor(p, 1);  p += __shfl_xor(p, 2);
      p += __shfl_xor(p, 4);  p += __shfl_xor(p, 8);
      p += __shfl_xor(p, 16); p += __shfl_xor(p, 32);
      if (l == 0){
        float s = p + alB[0];
        s = (s > 0.f) ? s : 0.01f*s;
        scorev[E0 + e] = s;
      }
    }
  }
}

// ---------------- per-atom: softmax + linear-attd context + ELU ----------------
// wave per atom; context = (attW·(Σ ex·nb) + (Σ ex)·bias) / (Σ ex + eps)
__global__ __launch_bounds__(256) void k_atom(
  const float* __restrict__ neighbor, const float* __restrict__ scorev,
  const int* __restrict__ rowstart, const int* __restrict__ elist,
  const float* __restrict__ attWt, const float* __restrict__ attBf,
  float* __restrict__ cfout)
{
  __shared__ float sWc[4096];
  __shared__ float sBias[64];
  int tid = threadIdx.x;
  int l = tid & 63;
  int w = tid >> 6;
  for (int i=tid; i<4096; i+=256) sWc[i] = attWt[i];
  if (tid < 64) sBias[tid] = attBf[tid];
  __syncthreads();

  int a = blockIdx.x*4 + w;     // 2500 blocks * 4 = 10000
  int s0 = rowstart[a], s1 = rowstart[a+1];

  float mx = -1e30f;
  for (int i=s0; i<s1; i++){
    float s = scorev[elist[i]];
    mx = fmaxf(mx, s);
  }
  float y = 0.f, dn = 0.f;
  for (int i=s0; i<s1; i++){
    int e = elist[i];
    float ex = expf(scorev[e] - mx);
    y = fmaf(ex, neighbor[(size_t)e*64 + l], y);
    dn += ex;
  }
  float ctxf = dn * sBias[l];
  #pragma unroll 4
  for (int k=0;k<64;k++){
    float yk = __shfl(y, k);
    ctxf = fmaf(yk, sWc[k*64 + l], ctxf);
  }
  float cf = ctxf / (dn + 1e-8f);
  cf = (cf > 0.f) ? cf : expm1f(cf);
  cfout[(size_t)a*64 + l] = cf;
}

// ---------------- per-atom: GRU ----------------
__global__ __launch_bounds__(256) void k_gru(
  const float* __restrict__ atom, const float* __restrict__ cfin,
  const float* __restrict__ wqG,
  const float* __restrict__ bih, const float* __restrict__ bhh,
  float* __restrict__ out)
{
  __shared__ float swq[24576];
  __shared__ float sc[4][8][64];
  __shared__ float shh[4][8][64];
  int tid = threadIdx.x;
  int f = tid & 63;
  int w = tid >> 6;
  for (int i=tid; i<6144; i+=256) ((f4*)swq)[i] = ((const f4*)wqG)[i];
  int base = blockIdx.x*32 + w*8;
  #pragma unroll
  for (int a=0; a<8; a++){
    int ga = base + a;
    float cf=0.f, hf=0.f;
    if (ga < NA){
      cf = cfin[(size_t)ga*64 + f];
      hf = atom[(size_t)ga*64 + f];
    }
    sc[w][a][f] = cf; shh[w][a][f] = hf;
  }
  __syncthreads();

  float acc[6][8];
  #pragma unroll
  for (int gg=0;gg<6;gg++)
    #pragma unroll
    for (int a=0;a<8;a++) acc[gg][a] = 0.f;

  for (int kg=0; kg<16; kg++){
    f4 wv[6];
    #pragma unroll
    for (int gg=0;gg<6;gg++) wv[gg] = *(const f4*)&swq[((gg*16+kg)*64 + f)*4];
    #pragma unroll
    for (int a=0;a<8;a++){
      f4 cv = *(const f4*)&sc[w][a][kg*4];
      f4 hv = *(const f4*)&shh[w][a][kg*4];
      #pragma unroll
      for (int j=0;j<4;j++){
        acc[0][a] = fmaf(cv[j], wv[0][j], acc[0][a]);
        acc[1][a] = fmaf(cv[j], wv[1][j], acc[1][a]);
        acc[2][a] = fmaf(cv[j], wv[2][j], acc[2][a]);
        acc[3][a] = fmaf(hv[j], wv[3][j], acc[3][a]);
        acc[4][a] = fmaf(hv[j], wv[4][j], acc[4][a]);
        acc[5][a] = fmaf(hv[j], wv[5][j], acc[5][a]);
      }
    }
  }

  float b0 = bih[f], b1 = bih[64+f], b2 = bih[128+f];
  float h0 = bhh[f], h1 = bhh[64+f], h2 = bhh[128+f];
  #pragma unroll
  for (int a=0;a<8;a++){
    int ga = base + a;
    if (ga < NA){
      float r = 1.f/(1.f + expf(-(acc[0][a] + b0 + acc[3][a] + h0)));
      float z = 1.f/(1.f + expf(-(acc[1][a] + b1 + acc[4][a] + h1)));
      float n = tanhf(acc[2][a] + b2 + r*(acc[5][a] + h2));
      out[(size_t)ga*64 + f] = (1.f - z)*n + z*shh[w][a][f];
    }
  }
}

extern "C" void kernel_launch(void* const* d_in, const int* in_sizes, int n_in,
                              void* d_out, int out_size, void* d_ws, size_t ws_size,
                              hipStream_t stream) {
  const float* atom = (const float*)d_in[0];
  const int*   bidx = (const int*)  d_in[1];
  const float* bond = (const float*)d_in[2];
  const float* encW = (const float*)d_in[3];
  const float* encB = (const float*)d_in[4];
  const float* eg   = (const float*)d_in[5];
  const float* ebt  = (const float*)d_in[6];
  const float* em   = (const float*)d_in[7];
  const float* ev   = (const float*)d_in[8];
  const float* alW  = (const float*)d_in[9];
  const float* alB  = (const float*)d_in[10];
  const float* atW  = (const float*)d_in[11];
  const float* atB  = (const float*)d_in[12];
  const float* agm  = (const float*)d_in[13];
  const float* abt  = (const float*)d_in[14];
  const float* amn  = (const float*)d_in[15];
  const float* avr  = (const float*)d_in[16];
  const float* wih  = (const float*)d_in[17];
  const float* whh  = (const float*)d_in[18];
  const float* bih  = (const float*)d_in[19];
  const float* bhh  = (const float*)d_in[20];

  float* ws = (float*)d_ws;
  unsigned short* Bh = (unsigned short*)(ws + 0);       // 65536 ush = 32768 f
  unsigned short* Bl = (unsigned short*)(ws + 32768);   // 32768 f
  float* attWt   = ws + 65536;    // 4096
  float* attBf   = ws + 69632;    // 64
  float* wq      = ws + 69696;    // 24576
  float* scorev  = ws + 94272;    // 40000
  int*   cnt     = (int*)(ws + 134272);   // 10000
  int*   rowstart= (int*)(ws + 144272);   // 10016 (10001 used)
  int*   wofs    = (int*)(ws + 154288);   // 10000
  int*   elist   = (int*)(ws + 164288);   // 40000
  float* cfout   = ws + 204288;   // 640000
  float* neighbor= ws + 844288;   // 2560000

  hipMemsetAsync(cnt, 0, NA*sizeof(int), stream);

  k_fold<<<512, 256, 0, stream>>>(encW,encB,eg,ebt,em,ev,
                                  atW,atB,agm,abt,amn,avr,
                                  wih,whh, Bh,Bl,attWt,attBf,wq);
  k_hist<<<(NE+255)/256, 256, 0, stream>>>(bidx, cnt);
  k_scan<<<1, 256, 0, stream>>>(cnt, rowstart, wofs);
  k_scatter<<<(NE+255)/256, 256, 0, stream>>>(bidx, wofs, elist);
  k_edge<<<1250, 256, 0, stream>>>(atom,bidx,bond,Bh,Bl,alW,alB,neighbor,scorev);
  k_atom<<<2500, 256, 0, stream>>>(neighbor,scorev,rowstart,elist,attWt,attBf,cfout);
  k_gru<<<313, 256, 0, stream>>>(atom,cfout,wq,bih,bhh,(float*)d_out);
}